// Round 13
// baseline (59.168 us; speedup 1.0000x reference)
//
#include <hip/hip_runtime.h>
#include <math.h>

#define SEQ   576     // H*W = 24*24
#define CDIM  96
#define INNER 192
#define NHEAD 48
#define DH    4
#define NB    2
#define EPSV  1e-5f
#define RT    64      // mlstm row-tile

__device__ __forceinline__ float silu_f(float x) { return x / (1.f + __expf(-x)); }
__device__ __forceinline__ float logsig_f(float x) {
    return (x >= 0.f) ? -log1pf(__expf(-x)) : (x - log1pf(__expf(x)));
}

// ====== K1: fused LN + up-proj (3-row halo) + conv + SiLU + q/k/v + gate GEMM ======
// grid 288 x 512: 4 own positions/block, 7 LN/xm rows (3 halo + 4 own).
// xm never round-trips through HBM; one kernel boundary removed vs the 4-kernel r12.
__global__ void __launch_bounds__(512) k_front(const float* __restrict__ x,
    const float* __restrict__ ln_g, const float* __restrict__ ln_b,
    const float* __restrict__ w_up, const float* __restrict__ b_up,
    const float* __restrict__ w_conv, const float* __restrict__ b_conv,
    const float* __restrict__ w_q, const float* __restrict__ b_q,
    const float* __restrict__ w_k, const float* __restrict__ b_k,
    const float* __restrict__ w_v, const float* __restrict__ b_v,
    const float* __restrict__ w_ig, const float* __restrict__ b_ig,
    const float* __restrict__ w_fg, const float* __restrict__ b_fg,
    float* __restrict__ z, float* __restrict__ xc,
    float* __restrict__ qw, float* __restrict__ kw, float* __restrict__ vw,
    float* __restrict__ igw, float* __restrict__ fgw) {
    const int t = threadIdx.x;
    const int p0 = blockIdx.x * 4;             // 4 own positions, same batch
    const int b = p0 / SEQ, s0 = p0 % SEQ;
    __shared__ __align__(16) float hbuf[7 * CDIM];   // LN rows ph=0..6 (ss = s0-3+ph)
    __shared__ __align__(16) float xmb[7 * INNER];
    __shared__ __align__(16) float xcb[4 * INNER];
    __shared__ __align__(16) float qkvb[4][3 * INNER];

    // ---- LN for 7 rows, one wave per row (wave 7 idle) ----
    {
        const int wv = t >> 6, l = t & 63;
        if (wv < 7) {
            const int ss = s0 - 3 + wv;
            if (ss >= 0) {
                const float v0 = x[(size_t)(b * CDIM + l) * SEQ + ss];
                const float v1 = (l < 32) ? x[(size_t)(b * CDIM + 64 + l) * SEQ + ss] : 0.f;
                float sum = v0 + v1, sq = v0 * v0 + v1 * v1;
                #pragma unroll
                for (int off = 1; off < 64; off <<= 1) {
                    sum += __shfl_xor(sum, off);
                    sq  += __shfl_xor(sq, off);
                }
                const float mean = sum * (1.f / CDIM);
                const float rstd = rsqrtf(sq * (1.f / CDIM) - mean * mean + EPSV);
                hbuf[wv * CDIM + l] = (v0 - mean) * rstd * ln_g[l] + ln_b[l];
                if (l < 32) hbuf[wv * CDIM + 64 + l] =
                    (v1 - mean) * rstd * ln_g[64 + l] + ln_b[64 + l];
            }
        }
    }
    __syncthreads();

    const int lane = t & 7, oi = t >> 3;       // 8 lanes/output, 64 groups in flight
    // ---- up-proj, xm half: 7 rows x 192 feats -> LDS (21 dots/thread) ----
    #pragma unroll 3
    for (int j = 0; j < 21; ++j) {
        const int idx = j * 64 + oi;           // 0..1343
        const int ph = idx / INNER, f = idx % INNER;
        const int ss = s0 - 3 + ph;
        if (ss < 0) {
            if (lane == 0) xmb[ph * INNER + f] = 0.f;   // causal zero-pad
            continue;
        }
        const float4* hr = (const float4*)(hbuf + ph * CDIM) + lane * 3;
        const float4* wr = (const float4*)(w_up + (size_t)f * CDIM) + lane * 3;
        const float4 h0 = hr[0], h1 = hr[1], h2 = hr[2];
        const float4 w0 = wr[0], w1 = wr[1], w2 = wr[2];
        float acc = h0.x*w0.x + h0.y*w0.y + h0.z*w0.z + h0.w*w0.w
                  + h1.x*w1.x + h1.y*w1.y + h1.z*w1.z + h1.w*w1.w
                  + h2.x*w2.x + h2.y*w2.y + h2.z*w2.z + h2.w*w2.w;
        #pragma unroll
        for (int off = 1; off < 8; off <<= 1) acc += __shfl_xor(acc, off);
        if (lane == 0) xmb[ph * INNER + f] = acc + b_up[f];
    }
    // ---- up-proj, z half: 4 own rows x 192 feats -> global (12 dots/thread) ----
    #pragma unroll 3
    for (int j = 0; j < 12; ++j) {
        const int idx = j * 64 + oi;           // 0..767
        const int ph = 3 + idx / INNER, f = idx % INNER;    // own rows 3..6
        const float4* hr = (const float4*)(hbuf + ph * CDIM) + lane * 3;
        const float4* wr = (const float4*)(w_up + (size_t)(INNER + f) * CDIM) + lane * 3;
        const float4 h0 = hr[0], h1 = hr[1], h2 = hr[2];
        const float4 w0 = wr[0], w1 = wr[1], w2 = wr[2];
        float acc = h0.x*w0.x + h0.y*w0.y + h0.z*w0.z + h0.w*w0.w
                  + h1.x*w1.x + h1.y*w1.y + h1.z*w1.z + h1.w*w1.w
                  + h2.x*w2.x + h2.y*w2.y + h2.z*w2.z + h2.w*w2.w;
        #pragma unroll
        for (int off = 1; off < 8; off <<= 1) acc += __shfl_xor(acc, off);
        if (lane == 0) z[(size_t)(p0 + ph - 3) * INNER + f] = acc + b_up[INNER + f];
    }
    __syncthreads();

    // ---- causal conv + SiLU (own 4 positions) ----
    for (int i = t; i < 4 * INNER; i += 512) {
        const int p = i / INNER, c = i % INNER;
        float acc = b_conv[c];
        #pragma unroll
        for (int j = 0; j < 4; ++j) acc += xmb[(p + j) * INNER + c] * w_conv[c * 4 + j];
        const float v = silu_f(acc);
        xcb[i] = v;
        xc[(size_t)(p0 + p) * INNER + c] = v;
    }
    __syncthreads();

    // ---- headwise q/k/v ----
    for (int i = t; i < 4 * INNER; i += 512) {
        const int p = i / INNER, c = i % INNER;
        const int n = c >> 2, o = c & 3;
        const float* wq = w_q + n * 16 + o * 4;
        const float* wk = w_k + n * 16 + o * 4;
        const float* wv = w_v + n * 16 + o * 4;
        float q = b_q[c], k = b_k[c], v = b_v[c];
        #pragma unroll
        for (int dd = 0; dd < 4; ++dd) {
            q += xcb[p * INNER + n * 4 + dd] * wq[dd];
            k += xcb[p * INNER + n * 4 + dd] * wk[dd];
            v += xmb[(p + 3) * INNER + n * 4 + dd] * wv[dd];
        }
        qkvb[p][c] = q; qkvb[p][INNER + c] = k; qkvb[p][2 * INNER + c] = v;
        const size_t base = ((size_t)(b * NHEAD + n) * SEQ + s0 + p) * DH + o;
        qw[base] = q; kw[base] = k; vw[base] = v;
    }
    __syncthreads();

    // ---- gates: 8 waves x 12 gates; 16 lanes/gate, weight row in regs reused x4 pos ----
    {
        const int w = t >> 6, l16 = t & 15, gg = (t >> 4) & 3;
        #pragma unroll
        for (int it = 0; it < 3; ++it) {
            const int g = w * 12 + it * 4 + gg;            // 0..95
            const bool isfg = (g >= NHEAD);
            const int hh = isfg ? (g - NHEAD) : g;
            const float4* wr = (const float4*)((isfg ? w_fg : w_ig) + (size_t)hh * 576) + l16 * 9;
            float4 wf[9];
            #pragma unroll
            for (int j = 0; j < 9; ++j) wf[j] = wr[j];
            #pragma unroll
            for (int p = 0; p < 4; ++p) {
                const float4* xr = (const float4*)(&qkvb[p][0]) + l16 * 9;
                float acc = 0.f;
                #pragma unroll
                for (int j = 0; j < 9; ++j) {
                    const float4 a = xr[j];
                    acc += a.x * wf[j].x + a.y * wf[j].y + a.z * wf[j].z + a.w * wf[j].w;
                }
                #pragma unroll
                for (int off = 1; off < 16; off <<= 1) acc += __shfl_xor(acc, off);
                if (l16 == 0) {
                    acc += isfg ? b_fg[hh] : b_ig[hh];
                    (isfg ? fgw : igw)[((size_t)b * NHEAD + hh) * SEQ + s0 + p] = acc;
                }
            }
        }
    }
}

// ------------- K2: mLSTM with fused per-block scan, 64-row tiles, 8 lanes/row -------------
// Dm[s,t] = exp(m[t] - M[s]); max_log_D[s] = lf_cum[s+1] + M[s]
__global__ void __launch_bounds__(512) k_mlstm(const float* __restrict__ qw,
    const float* __restrict__ kw, const float* __restrict__ vw,
    const float* __restrict__ igw, const float* __restrict__ fgw,
    float* __restrict__ ht) {
    const int bh = blockIdx.x;          // 96
    const int r0 = blockIdx.y * RT;     // 9 tiles of 64 rows
    const int nt = r0 + RT;
    const int t = threadIdx.x;          // 512 = 64 rows x 8 lanes
    __shared__ float4 k4[SEQ], v4[SEQ];
    __shared__ float m_l[SEQ], M_l[SEQ], lfc_l[SEQ];

    const float4* kb = (const float4*)(kw + (size_t)bh * SEQ * DH);
    const float4* vb = (const float4*)(vw + (size_t)bh * SEQ * DH);
    for (int i = t; i < nt; i += 512) { k4[i] = kb[i]; v4[i] = vb[i]; }

    if (t < 64) {                // wave-0 scans: lf_cum, m, prefix-max M
        const int base = t * 9;
        float pre[9], mv[9], mx[9];
        float run = 0.f;
        #pragma unroll
        for (int j = 0; j < 9; ++j) {
            run += logsig_f(fgw[(size_t)bh * SEQ + base + j]);
            pre[j] = run;
        }
        float incl = run;
        #pragma unroll
        for (int off = 1; off < 64; off <<= 1) {
            float o = __shfl_up(incl, off);
            if (t >= off) incl += o;
        }
        const float excl = incl - run;
        float runm = -INFINITY;
        #pragma unroll
        for (int j = 0; j < 9; ++j) {
            float lfc = excl + pre[j];                  // lf_cum[t+1]
            lfc_l[base + j] = lfc;
            float mt = igw[(size_t)bh * SEQ + base + j] - lfc;
            mv[j] = mt;
            runm = fmaxf(runm, mt);
            mx[j] = runm;
        }
        float sc = runm;
        #pragma unroll
        for (int off = 1; off < 64; off <<= 1) {
            float o = __shfl_up(sc, off);
            if (t >= off) sc = fmaxf(sc, o);
        }
        float exclm = __shfl_up(sc, 1);
        if (t == 0) exclm = -INFINITY;
        #pragma unroll
        for (int j = 0; j < 9; ++j) {
            m_l[base + j] = mv[j];
            M_l[base + j] = fmaxf(exclm, mx[j]);
        }
    }
    __syncthreads();

    const int lane = t & 7;
    const int s0 = r0 + (t >> 3);
    const float4 q = ((const float4*)(qw + (size_t)bh * SEQ * DH))[s0];
    const float Ms = M_l[s0], lfcs = lfc_l[s0];

    float a0 = 0.f, a1 = 0.f, a2 = 0.f, a3 = 0.f, csum = 0.f;
    for (int tt = lane; tt <= s0; tt += 8) {
        const float e = __expf(m_l[tt] - Ms);
        const float4 kk = k4[tt], vv = v4[tt];
        const float c = (q.x*kk.x + q.y*kk.y + q.z*kk.z + q.w*kk.w) * 0.5f * e;  // DH^-0.5
        csum += c;
        a0 += c * vv.x; a1 += c * vv.y; a2 += c * vv.z; a3 += c * vv.w;
    }
    #pragma unroll
    for (int off = 1; off < 8; off <<= 1) {
        csum += __shfl_xor(csum, off);
        a0 += __shfl_xor(a0, off); a1 += __shfl_xor(a1, off);
        a2 += __shfl_xor(a2, off); a3 += __shfl_xor(a3, off);
    }
    if (lane == 0) {
        const float floorv = __expf(-(lfcs + Ms));
        const float inv = 1.f / (fmaxf(fabsf(csum), floorv) + 1e-6f);
        ((float4*)ht)[(size_t)bh * SEQ + s0] =
            make_float4(a0 * inv, a1 * inv, a2 * inv, a3 * inv);
    }
}

// ------------- K3: epilogue: mhLN + skip + z-gate (phase 1), down-GEMM + residual ----
// grid (576) x 256: 2 positions/block.
__global__ void __launch_bounds__(256) k_epi(const float* __restrict__ ht,
    const float* __restrict__ on_g, const float* __restrict__ on_b,
    const float* __restrict__ skip, const float* __restrict__ xc,
    const float* __restrict__ zz, const float* __restrict__ w_down,
    const float* __restrict__ b_down, const float* __restrict__ x,
    float* __restrict__ out) {
    const int t = threadIdx.x;
    const int p0 = blockIdx.x * 2;
    const int b = p0 / SEQ;
    __shared__ __align__(16) float hs[2][INNER];

    for (int i = t; i < 2 * INNER; i += 256) {
        const int p = i / INNER, c = i % INNER;
        const int pos = p0 + p, s = pos % SEQ;
        const int n = c >> 2, o = c & 3;
        const float4 hv = ((const float4*)ht)[(size_t)(b * NHEAD + n) * SEQ + s];
        const float mean = (hv.x + hv.y + hv.z + hv.w) * 0.25f;
        const float d0 = hv.x - mean, d1 = hv.y - mean, d2 = hv.z - mean, d3 = hv.w - mean;
        const float var = (d0*d0 + d1*d1 + d2*d2 + d3*d3) * 0.25f;
        const float rstd = rsqrtf(var + EPSV);
        const float he = (o == 0) ? hv.x : (o == 1) ? hv.y : (o == 2) ? hv.z : hv.w;
        const float hn = (he - mean) * rstd * on_g[c] + on_b[c];
        const float hk = hn + skip[c] * xc[(size_t)pos * INNER + c];
        hs[p][c] = hk * silu_f(zz[(size_t)pos * INNER + c]);
    }
    __syncthreads();

    const int lane = t & 7, oi = t >> 3;       // 32 groups
    const int p2 = oi & 1, cg2 = oi >> 1;      // 2 pos x 16 channel-groups
    const int pos = p0 + p2, s = pos % SEQ;
    const float4* hr = (const float4*)(&hs[p2][0]) + lane * 6;
    float4 h4[6];
    #pragma unroll
    for (int j = 0; j < 6; ++j) h4[j] = hr[j];
    #pragma unroll
    for (int j = 0; j < 6; ++j) {
        const int c = cg2 + 16 * j;            // 0..95
        const float4* wr = (const float4*)(w_down + (size_t)c * INNER) + lane * 6;
        float acc = 0.f;
        #pragma unroll
        for (int u = 0; u < 6; ++u) {
            const float4 w = wr[u];
            acc += h4[u].x*w.x + h4[u].y*w.y + h4[u].z*w.z + h4[u].w*w.w;
        }
        #pragma unroll
        for (int off = 1; off < 8; off <<= 1) acc += __shfl_xor(acc, off);
        if (lane == 0) {
            const size_t idx = ((size_t)b * CDIM + c) * SEQ + s;
            out[idx] = x[idx] + acc + b_down[c];
        }
    }
}

extern "C" void kernel_launch(void* const* d_in, const int* in_sizes, int n_in,
                              void* d_out, int out_size, void* d_ws, size_t ws_size,
                              hipStream_t stream) {
    const float* x      = (const float*)d_in[0];
    const float* ln_g   = (const float*)d_in[1];
    const float* ln_b   = (const float*)d_in[2];
    const float* w_up   = (const float*)d_in[3];
    const float* b_up   = (const float*)d_in[4];
    const float* w_q    = (const float*)d_in[5];
    const float* b_q    = (const float*)d_in[6];
    const float* w_k    = (const float*)d_in[7];
    const float* b_k    = (const float*)d_in[8];
    const float* w_v    = (const float*)d_in[9];
    const float* b_v    = (const float*)d_in[10];
    const float* w_conv = (const float*)d_in[11];
    const float* b_conv = (const float*)d_in[12];
    const float* w_ig   = (const float*)d_in[13];
    const float* b_ig   = (const float*)d_in[14];
    const float* w_fg   = (const float*)d_in[15];
    const float* b_fg   = (const float*)d_in[16];
    const float* on_g   = (const float*)d_in[17];
    const float* on_b   = (const float*)d_in[18];
    const float* skip   = (const float*)d_in[19];
    const float* w_down = (const float*)d_in[20];
    const float* b_down = (const float*)d_in[21];

    float* ws = (float*)d_ws;
    const size_t NSI = (size_t)NB * SEQ * INNER;       // 221184
    const size_t NHS = (size_t)NB * NHEAD * SEQ;       // 55296
    float* z   = ws;                // [B*S][192]
    float* xc  = z + NSI;
    float* qw  = xc + NSI;          // head-major [B][NH][S][4]
    float* kw  = qw + NSI;
    float* vw  = kw + NSI;
    float* igw = vw + NSI;          // [B][NH][S]
    float* fgw = igw + NHS;
    float* ht  = fgw + NHS;         // [B][NH][S][4]

    float* out = (float*)d_out;

    hipLaunchKernelGGL(k_front, dim3(NB * SEQ / 4), dim3(512), 0, stream,
                       x, ln_g, ln_b, w_up, b_up, w_conv, b_conv,
                       w_q, b_q, w_k, b_k, w_v, b_v, w_ig, b_ig, w_fg, b_fg,
                       z, xc, qw, kw, vw, igw, fgw);
    hipLaunchKernelGGL(k_mlstm, dim3(NB * NHEAD, SEQ / RT), dim3(512), 0, stream,
                       qw, kw, vw, igw, fgw, ht);
    hipLaunchKernelGGL(k_epi, dim3(NB * SEQ / 2), dim3(256), 0, stream,
                       ht, on_g, on_b, skip, xc, z, w_down, b_down, x, out);
}

// Round 14
// 54.658 us; speedup vs baseline: 1.0825x; 1.0825x over previous
//
#include <hip/hip_runtime.h>
#include <math.h>

#define SEQ   576     // H*W = 24*24
#define CDIM  96
#define INNER 192
#define NHEAD 48
#define DH    4
#define NB    2
#define EPSV  1e-5f
#define RT    64      // mlstm row-tile

__device__ __forceinline__ float silu_f(float x) { return x / (1.f + __expf(-x)); }
__device__ __forceinline__ float logsig_f(float x) {
    return (x >= 0.f) ? -log1pf(__expf(-x)) : (x - log1pf(__expf(x)));
}

// ---------------- K1: fused LayerNorm + up-proj GEMM ----------------
// grid (288, 2) x 512: 4 positions/block, 192-feature output slice per block.
__global__ void __launch_bounds__(512) k_ln_up(const float* __restrict__ x,
    const float* __restrict__ ln_g, const float* __restrict__ ln_b,
    const float* __restrict__ w_up, const float* __restrict__ b_up,
    float* __restrict__ xm, float* __restrict__ z) {
    const int t = threadIdx.x;
    const int p0 = blockIdx.x * 4;             // 4 positions, same batch
    const int b = p0 / SEQ;
    const int f0 = blockIdx.y * 192;
    __shared__ __align__(16) float hbuf[4 * CDIM];

    // phase 1: LN for 4 positions (one wave each; waves 4-7 idle briefly)
    {
        const int p = t >> 6, l = t & 63;
        if (p < 4) {
            const int s = (p0 + p) % SEQ;
            const float v0 = x[(size_t)(b * CDIM + l) * SEQ + s];
            const float v1 = (l < 32) ? x[(size_t)(b * CDIM + 64 + l) * SEQ + s] : 0.f;
            float sum = v0 + v1, sq = v0 * v0 + v1 * v1;
            #pragma unroll
            for (int off = 1; off < 64; off <<= 1) {
                sum += __shfl_xor(sum, off);
                sq  += __shfl_xor(sq, off);
            }
            const float mean = sum * (1.f / CDIM);
            const float rstd = rsqrtf(sq * (1.f / CDIM) - mean * mean + EPSV);
            hbuf[p * CDIM + l] = (v0 - mean) * rstd * ln_g[l] + ln_b[l];
            if (l < 32) hbuf[p * CDIM + 64 + l] = (v1 - mean) * rstd * ln_g[64 + l] + ln_b[64 + l];
        }
    }
    __syncthreads();

    // phase 2: 4 pos x 192 feats, 8 lanes/output, 12 sequential feats/thread
    const int lane = t & 7, oi = t >> 3;       // 64 groups
    const int p2 = oi & 3, fg = oi >> 2;       // 4 pos x 16 feat-groups
    const int pos = p0 + p2;
    const float4* hr = (const float4*)(hbuf + p2 * CDIM) + lane * 3;
    const float4 h0 = hr[0], h1 = hr[1], h2 = hr[2];
    #pragma unroll 4
    for (int j = 0; j < 12; ++j) {
        const int f = f0 + fg + 16 * j;
        const float4* wr = (const float4*)(w_up + (size_t)f * CDIM) + lane * 3;
        const float4 w0 = wr[0], w1 = wr[1], w2 = wr[2];
        float acc = h0.x*w0.x + h0.y*w0.y + h0.z*w0.z + h0.w*w0.w
                  + h1.x*w1.x + h1.y*w1.y + h1.z*w1.z + h1.w*w1.w
                  + h2.x*w2.x + h2.y*w2.y + h2.z*w2.z + h2.w*w2.w;
        #pragma unroll
        for (int off = 1; off < 8; off <<= 1) acc += __shfl_xor(acc, off);
        if (lane == 0) {
            acc += b_up[f];
            if (f < INNER) xm[(size_t)pos * INNER + f] = acc;
            else           z [(size_t)pos * INNER + (f - INNER)] = acc;
        }
    }
}

// ------------- K2: causal conv + SiLU + headwise q/k/v + gate GEMM -------------
// grid (288) x 512: 4 positions/block.
__global__ void __launch_bounds__(512) k_conv_qkv_gates(const float* __restrict__ xm,
    const float* __restrict__ w_conv, const float* __restrict__ b_conv,
    const float* __restrict__ w_q, const float* __restrict__ b_q,
    const float* __restrict__ w_k, const float* __restrict__ b_k,
    const float* __restrict__ w_v, const float* __restrict__ b_v,
    const float* __restrict__ w_ig, const float* __restrict__ b_ig,
    const float* __restrict__ w_fg, const float* __restrict__ b_fg,
    float* __restrict__ xc, float* __restrict__ qw, float* __restrict__ kw,
    float* __restrict__ vw, float* __restrict__ igw, float* __restrict__ fgw) {
    const int t = threadIdx.x;
    const int p0 = blockIdx.x * 4;
    const int b = p0 / SEQ, s0 = p0 % SEQ;
    __shared__ float xmb[7][INNER];            // xm rows s0-3 .. s0+3
    __shared__ float xcb[4][INNER];
    __shared__ __align__(16) float qkvb[4][3 * INNER];

    for (int i = t; i < 7 * INNER; i += 512) {
        const int r = i / INNER, c = i % INNER;
        const int ss = s0 - 3 + r;
        xmb[r][c] = (ss >= 0) ? xm[(size_t)(b * SEQ + ss) * INNER + c] : 0.f;
    }
    __syncthreads();

    for (int i = t; i < 4 * INNER; i += 512) {
        const int p = i / INNER, c = i % INNER;
        float acc = b_conv[c];
        #pragma unroll
        for (int j = 0; j < 4; ++j) acc += xmb[p + j][c] * w_conv[c * 4 + j];
        const float v = silu_f(acc);
        xcb[p][c] = v;
        xc[(size_t)(b * SEQ + s0 + p) * INNER + c] = v;
    }
    __syncthreads();

    for (int i = t; i < 4 * INNER; i += 512) {
        const int p = i / INNER, c = i % INNER;
        const int n = c >> 2, o = c & 3;
        const float* wq = w_q + n * 16 + o * 4;
        const float* wk = w_k + n * 16 + o * 4;
        const float* wv = w_v + n * 16 + o * 4;
        float q = b_q[c], k = b_k[c], v = b_v[c];
        #pragma unroll
        for (int dd = 0; dd < 4; ++dd) {
            q += xcb[p][n * 4 + dd] * wq[dd];
            k += xcb[p][n * 4 + dd] * wk[dd];
            v += xmb[p + 3][n * 4 + dd] * wv[dd];
        }
        qkvb[p][c] = q; qkvb[p][INNER + c] = k; qkvb[p][2 * INNER + c] = v;
        const size_t base = ((size_t)(b * NHEAD + n) * SEQ + s0 + p) * DH + o;
        qw[base] = q; kw[base] = k; vw[base] = v;
    }
    __syncthreads();

    {   // gates: 8 waves x 12 gates; 16 lanes/gate, weight row in regs reused x4 pos
        const int w = t >> 6, l16 = t & 15, gg = (t >> 4) & 3;
        #pragma unroll
        for (int it = 0; it < 3; ++it) {
            const int g = w * 12 + it * 4 + gg;            // 0..95
            const bool isfg = (g >= NHEAD);
            const int hh = isfg ? (g - NHEAD) : g;
            const float4* wr = (const float4*)((isfg ? w_fg : w_ig) + (size_t)hh * 576) + l16 * 9;
            float4 wf[9];
            #pragma unroll
            for (int j = 0; j < 9; ++j) wf[j] = wr[j];
            #pragma unroll
            for (int p = 0; p < 4; ++p) {
                const float4* xr = (const float4*)(&qkvb[p][0]) + l16 * 9;
                float acc = 0.f;
                #pragma unroll
                for (int j = 0; j < 9; ++j) {
                    const float4 a = xr[j];
                    acc += a.x * wf[j].x + a.y * wf[j].y + a.z * wf[j].z + a.w * wf[j].w;
                }
                #pragma unroll
                for (int off = 1; off < 16; off <<= 1) acc += __shfl_xor(acc, off);
                if (l16 == 0) {
                    acc += isfg ? b_fg[hh] : b_ig[hh];
                    (isfg ? fgw : igw)[((size_t)b * NHEAD + hh) * SEQ + s0 + p] = acc;
                }
            }
        }
    }
}

// ------------- K3: mLSTM with fused per-block scan, 64-row tiles, 8 lanes/row -------------
// Dm[s,t] = exp(m[t] - M[s]); max_log_D[s] = lf_cum[s+1] + M[s]
__global__ void __launch_bounds__(512) k_mlstm(const float* __restrict__ qw,
    const float* __restrict__ kw, const float* __restrict__ vw,
    const float* __restrict__ igw, const float* __restrict__ fgw,
    float* __restrict__ ht) {
    const int bh = blockIdx.x;          // 96
    const int r0 = blockIdx.y * RT;     // 9 tiles of 64 rows
    const int nt = r0 + RT;
    const int t = threadIdx.x;          // 512 = 64 rows x 8 lanes
    __shared__ float4 k4[SEQ], v4[SEQ];
    __shared__ float m_l[SEQ], M_l[SEQ], lfc_l[SEQ];

    const float4* kb = (const float4*)(kw + (size_t)bh * SEQ * DH);
    const float4* vb = (const float4*)(vw + (size_t)bh * SEQ * DH);
    for (int i = t; i < nt; i += 512) { k4[i] = kb[i]; v4[i] = vb[i]; }

    if (t < 64) {                // wave-0 scans: lf_cum, m, prefix-max M
        const int base = t * 9;
        float pre[9], mv[9], mx[9];
        float run = 0.f;
        #pragma unroll
        for (int j = 0; j < 9; ++j) {
            run += logsig_f(fgw[(size_t)bh * SEQ + base + j]);
            pre[j] = run;
        }
        float incl = run;
        #pragma unroll
        for (int off = 1; off < 64; off <<= 1) {
            float o = __shfl_up(incl, off);
            if (t >= off) incl += o;
        }
        const float excl = incl - run;
        float runm = -INFINITY;
        #pragma unroll
        for (int j = 0; j < 9; ++j) {
            float lfc = excl + pre[j];                  // lf_cum[t+1]
            lfc_l[base + j] = lfc;
            float mt = igw[(size_t)bh * SEQ + base + j] - lfc;
            mv[j] = mt;
            runm = fmaxf(runm, mt);
            mx[j] = runm;
        }
        float sc = runm;
        #pragma unroll
        for (int off = 1; off < 64; off <<= 1) {
            float o = __shfl_up(sc, off);
            if (t >= off) sc = fmaxf(sc, o);
        }
        float exclm = __shfl_up(sc, 1);
        if (t == 0) exclm = -INFINITY;
        #pragma unroll
        for (int j = 0; j < 9; ++j) {
            m_l[base + j] = mv[j];
            M_l[base + j] = fmaxf(exclm, mx[j]);
        }
    }
    __syncthreads();

    const int lane = t & 7;
    const int s0 = r0 + (t >> 3);
    const float4 q = ((const float4*)(qw + (size_t)bh * SEQ * DH))[s0];
    const float Ms = M_l[s0], lfcs = lfc_l[s0];

    float a0 = 0.f, a1 = 0.f, a2 = 0.f, a3 = 0.f, csum = 0.f;
    for (int tt = lane; tt <= s0; tt += 8) {
        const float e = __expf(m_l[tt] - Ms);
        const float4 kk = k4[tt], vv = v4[tt];
        const float c = (q.x*kk.x + q.y*kk.y + q.z*kk.z + q.w*kk.w) * 0.5f * e;  // DH^-0.5
        csum += c;
        a0 += c * vv.x; a1 += c * vv.y; a2 += c * vv.z; a3 += c * vv.w;
    }
    #pragma unroll
    for (int off = 1; off < 8; off <<= 1) {
        csum += __shfl_xor(csum, off);
        a0 += __shfl_xor(a0, off); a1 += __shfl_xor(a1, off);
        a2 += __shfl_xor(a2, off); a3 += __shfl_xor(a3, off);
    }
    if (lane == 0) {
        const float floorv = __expf(-(lfcs + Ms));
        const float inv = 1.f / (fmaxf(fabsf(csum), floorv) + 1e-6f);
        ((float4*)ht)[(size_t)bh * SEQ + s0] =
            make_float4(a0 * inv, a1 * inv, a2 * inv, a3 * inv);
    }
}

// ------------- K4: epilogue: mhLN + skip + z-gate (phase 1), down-GEMM + residual ----
// grid (576) x 256: 2 positions/block.
__global__ void __launch_bounds__(256) k_epi(const float* __restrict__ ht,
    const float* __restrict__ on_g, const float* __restrict__ on_b,
    const float* __restrict__ skip, const float* __restrict__ xc,
    const float* __restrict__ zz, const float* __restrict__ w_down,
    const float* __restrict__ b_down, const float* __restrict__ x,
    float* __restrict__ out) {
    const int t = threadIdx.x;
    const int p0 = blockIdx.x * 2;
    const int b = p0 / SEQ;
    __shared__ __align__(16) float hs[2][INNER];

    for (int i = t; i < 2 * INNER; i += 256) {
        const int p = i / INNER, c = i % INNER;
        const int pos = p0 + p, s = pos % SEQ;
        const int n = c >> 2, o = c & 3;
        const float4 hv = ((const float4*)ht)[(size_t)(b * NHEAD + n) * SEQ + s];
        const float mean = (hv.x + hv.y + hv.z + hv.w) * 0.25f;
        const float d0 = hv.x - mean, d1 = hv.y - mean, d2 = hv.z - mean, d3 = hv.w - mean;
        const float var = (d0*d0 + d1*d1 + d2*d2 + d3*d3) * 0.25f;
        const float rstd = rsqrtf(var + EPSV);
        const float he = (o == 0) ? hv.x : (o == 1) ? hv.y : (o == 2) ? hv.z : hv.w;
        const float hn = (he - mean) * rstd * on_g[c] + on_b[c];
        const float hk = hn + skip[c] * xc[(size_t)pos * INNER + c];
        hs[p][c] = hk * silu_f(zz[(size_t)pos * INNER + c]);
    }
    __syncthreads();

    const int lane = t & 7, oi = t >> 3;       // 32 groups
    const int p2 = oi & 1, cg2 = oi >> 1;      // 2 pos x 16 channel-groups
    const int pos = p0 + p2, s = pos % SEQ;
    const float4* hr = (const float4*)(&hs[p2][0]) + lane * 6;
    float4 h4[6];
    #pragma unroll
    for (int j = 0; j < 6; ++j) h4[j] = hr[j];
    #pragma unroll
    for (int j = 0; j < 6; ++j) {
        const int c = cg2 + 16 * j;            // 0..95
        const float4* wr = (const float4*)(w_down + (size_t)c * INNER) + lane * 6;
        float acc = 0.f;
        #pragma unroll
        for (int u = 0; u < 6; ++u) {
            const float4 w = wr[u];
            acc += h4[u].x*w.x + h4[u].y*w.y + h4[u].z*w.z + h4[u].w*w.w;
        }
        #pragma unroll
        for (int off = 1; off < 8; off <<= 1) acc += __shfl_xor(acc, off);
        if (lane == 0) {
            const size_t idx = ((size_t)b * CDIM + c) * SEQ + s;
            out[idx] = x[idx] + acc + b_down[c];
        }
    }
}

extern "C" void kernel_launch(void* const* d_in, const int* in_sizes, int n_in,
                              void* d_out, int out_size, void* d_ws, size_t ws_size,
                              hipStream_t stream) {
    const float* x      = (const float*)d_in[0];
    const float* ln_g   = (const float*)d_in[1];
    const float* ln_b   = (const float*)d_in[2];
    const float* w_up   = (const float*)d_in[3];
    const float* b_up   = (const float*)d_in[4];
    const float* w_q    = (const float*)d_in[5];
    const float* b_q    = (const float*)d_in[6];
    const float* w_k    = (const float*)d_in[7];
    const float* b_k    = (const float*)d_in[8];
    const float* w_v    = (const float*)d_in[9];
    const float* b_v    = (const float*)d_in[10];
    const float* w_conv = (const float*)d_in[11];
    const float* b_conv = (const float*)d_in[12];
    const float* w_ig   = (const float*)d_in[13];
    const float* b_ig   = (const float*)d_in[14];
    const float* w_fg   = (const float*)d_in[15];
    const float* b_fg   = (const float*)d_in[16];
    const float* on_g   = (const float*)d_in[17];
    const float* on_b   = (const float*)d_in[18];
    const float* skip   = (const float*)d_in[19];
    const float* w_down = (const float*)d_in[20];
    const float* b_down = (const float*)d_in[21];

    float* ws = (float*)d_ws;
    const size_t NSI = (size_t)NB * SEQ * INNER;       // 221184
    const size_t NHS = (size_t)NB * NHEAD * SEQ;       // 55296
    float* xm  = ws;                // x_mlstm [B*S][192]
    float* z   = xm + NSI;
    float* xc  = z + NSI;
    float* qw  = xc + NSI;          // head-major [B][NH][S][4]
    float* kw  = qw + NSI;
    float* vw  = kw + NSI;
    float* igw = vw + NSI;          // [B][NH][S]
    float* fgw = igw + NHS;
    float* ht  = fgw + NHS;         // [B][NH][S][4]

    float* out = (float*)d_out;

    hipLaunchKernelGGL(k_ln_up, dim3(NB * SEQ / 4, 2), dim3(512), 0, stream,
                       x, ln_g, ln_b, w_up, b_up, xm, z);
    hipLaunchKernelGGL(k_conv_qkv_gates, dim3(NB * SEQ / 4), dim3(512), 0, stream,
                       xm, w_conv, b_conv, w_q, b_q, w_k, b_k, w_v, b_v,
                       w_ig, b_ig, w_fg, b_fg, xc, qw, kw, vw, igw, fgw);
    hipLaunchKernelGGL(k_mlstm, dim3(NB * NHEAD, SEQ / RT), dim3(512), 0, stream,
                       qw, kw, vw, igw, fgw, ht);
    hipLaunchKernelGGL(k_epi, dim3(NB * SEQ / 2), dim3(256), 0, stream,
                       ht, on_g, on_b, skip, xc, z, w_down, b_down, x, out);
}